// Round 18
// baseline (118.809 us; speedup 1.0000x reference)
//
#include <hip/hip_runtime.h>

// VectorGauntTensorProduct — factored algebraic collapse, SINGLE kernel with
// producer-consumer flag (no cooperative API — r17 showed it never launches
// in this harness: absmax matched the empty-stub round exactly).
//
// r18 = r16 fused: blocks 0..624 compute T (one entry/wave), 625..630 compute
// V; ALL blocks overlap x/y staging + P compute; producers release-add a
// device-scope counter; everyone acquire-spins to cnt==631; then r16 phase 2.
// Co-residency guaranteed: 29.7 KB LDS -> 5 blocks/CU capacity >= 4 needed
// (1024 blocks / 256 CUs), __launch_bounds__(256) declared.
//
// T[t,pq]  = sum_g wq[g] Yin[g,s] Yin[g,sp] Yout[g,t]       (25x100, block-padded)
// V[lt,b,d]= sum_c Wx[ls,c] Wy[lsp,c] Wz[lt,c,d]            (stride-292 rows)
// P[row,pq]= x[n,a,s] y[n,b,sp] - x[n,b,s] y[n,a,sp]        (row = ni*3+v)
// Z[row,t,b] = sum_{pq in block b} P[row,pq] T[t,pq]
// out[n,d,v,t] = sum_b Z[row,t,b] V[l(t),b,d]
//
// Padded block layout: b = ls*3+lsp, sizes {1,3,5,3,9,15,5,15,25} padded to
// {4,4,8,4,12,16,8,16,28}, starts {0,4,8,16,20,32,48,56,72}, total 100.
// Pads are 0.0 in BOTH T and P.
//
// BUG HISTORY: r4 overlay race; r4-r6 `if(tid<N)` staging bug (STRIDED loops
// only). r9->r10: no direct scatter stores. r15: occupancy beats instruction
// count. r16: T/V from global = neutral. r17: hipLaunchCooperativeKernel never
// runs here (stub-identical absmax) — use flag-based producer/consumer sync.

#define GG 380

__device__ __forceinline__ bool decode2(int pq, int& s, int& sp) {
    int b, off;
    if (pq < 16) {
        if (pq < 4)       { b = 0; off = pq; }
        else if (pq < 8)  { b = 1; off = pq - 4; }
        else              { b = 2; off = pq - 8; }
    } else if (pq < 48) {
        if (pq < 20)      { b = 3; off = pq - 16; }
        else if (pq < 32) { b = 4; off = pq - 20; }
        else              { b = 5; off = pq - 32; }
    } else {
        if (pq < 56)      { b = 6; off = pq - 48; }
        else if (pq < 72) { b = 7; off = pq - 56; }
        else              { b = 8; off = pq - 72; }
    }
    int ls = b / 3, lsp = b % 3, w = 2 * lsp + 1;
    if (off >= (2 * ls + 1) * w) return false;
    s  = ls * ls + off / w;
    sp = lsp * lsp + off % w;
    return true;
}

// LDS floats: xs[0,108)* ys[108,216)* Ps[216,816) Z[816,2616) Zout[2616,7416)
__global__ __launch_bounds__(256) void gaunt_fused(
        const float* __restrict__ x,  const float* __restrict__ y,
        const float* __restrict__ Wx, const float* __restrict__ Wy,
        const float* __restrict__ Wz, const float* __restrict__ Yin,
        const float* __restrict__ Yout, const float* __restrict__ wq,
        float* __restrict__ Tg, float* __restrict__ Vg,
        unsigned int* __restrict__ cnt,
        float* __restrict__ out) {
    __shared__ __align__(16) float smem[7416];
    float* xs   = smem;            // 54 used
    float* ys   = smem + 108;      // 54 used
    float* Ps   = smem + 216;      // 6*100
    float* Z    = smem + 816;      // 6*300
    float* Zout = smem + 2616;     // 4800

    const int tid = threadIdx.x;
    const int bid = blockIdx.x;
    const int n0 = bid * 2;

    // ---------------- phase 1a: producers write T / V ----------------
    if (bid < 625) {
        const int W = bid * 4 + (tid >> 6);       // 0..2499 = t*100 + pq
        const int lane = tid & 63;
        const int t = W / 100, pq = W % 100;
        int s, sp;
        float acc = 0.f;
        if (decode2(pq, s, sp)) {
#pragma unroll
            for (int i = 0; i < 6; ++i) {
                int g = lane + 64 * i;
                if (g < GG)
                    acc = fmaf(wq[g] * Yin[g * 9 + s],
                               Yin[g * 9 + sp] * Yout[g * 25 + t], acc);
            }
        }
#pragma unroll
        for (int m = 32; m; m >>= 1) acc += __shfl_xor(acc, m, 64);
        if (lane == 0) Tg[W] = acc;               // pads write 0
    } else if (bid < 631) {
        const int idx = (bid - 625) * 256 + tid;
        if (idx < 1460) {                          // V: 5 rows * 292 (incl pads)
            int lt = idx / 292, r = idx % 292;
            float acc = 0.f;
            if (r < 288) {
                int b = r / 32, d = r % 32;
                int ls = b / 3, lsp = b % 3;
                for (int c = 0; c < 32; ++c)
                    acc = fmaf(Wx[ls * 32 + c] * Wy[lsp * 32 + c],
                               Wz[lt * 1024 + c * 32 + d], acc);
            }
            Vg[idx] = acc;                         // pad slots -> 0
        }
    }
    if (bid < 631) {                               // producer signals completion
        __syncthreads();                           // all its waves' writes done
        if (tid == 0) {
            __threadfence();                       // release T/V to device scope
            __hip_atomic_fetch_add(cnt, 1u, __ATOMIC_RELEASE,
                                   __HIP_MEMORY_SCOPE_AGENT);
        }
    }

    // ---- phase 1b (all blocks, overlaps producers): x/y stage, P ----
    if (tid < 54)       xs[tid]      = x[n0 * 27 + tid];
    else if (tid < 108) ys[tid - 54] = y[n0 * 27 + tid - 54];
    __syncthreads();

    for (int idx = tid; idx < 600; idx += 256) {   // P[row][100], pads zero
        int row = idx / 100, pq = idx % 100;
        float v = 0.f;
        int s, sp;
        if (decode2(pq, s, sp)) {
            int ni = row / 3, vv = row % 3;
            int a = (vv == 0) ? 1 : ((vv == 1) ? 2 : 0);
            int b = (vv == 0) ? 2 : ((vv == 1) ? 0 : 1);
            v = xs[ni * 27 + a * 9 + s] * ys[ni * 27 + b * 9 + sp]
              - xs[ni * 27 + b * 9 + s] * ys[ni * 27 + a * 9 + sp];
        }
        Ps[idx] = v;
    }

    // ---- wait for all 631 producers (co-resident by capacity: 5/CU >= 4) ----
    if (tid == 0) {
        while (__hip_atomic_load(cnt, __ATOMIC_ACQUIRE,
                                 __HIP_MEMORY_SCOPE_AGENT) < 631u)
            __builtin_amdgcn_s_sleep(2);
    }
    __syncthreads();

    // ---------------- phase 2 (r16 verbatim) ----------------
#define DOT4(c, accv) { float4 pv = P4[c], tv = T4[c];                      \
        accv = fmaf(pv.x, tv.x, accv); accv = fmaf(pv.y, tv.y, accv);       \
        accv = fmaf(pv.z, tv.z, accv); accv = fmaf(pv.w, tv.w, accv); }
    if (tid < 150) {
        int t = tid / 6, row = tid % 6;
        const float4* P4 = (const float4*)(Ps + row * 100);
        const float4* T4 = (const float4*)(Tg + t * 100);   // global, L2-warm
        float a0 = 0.f, a1 = 0.f, a2 = 0.f, a3 = 0.f, a4 = 0.f,
              a5 = 0.f, a6 = 0.f, a7 = 0.f, a8 = 0.f;
        DOT4(0, a0)
        DOT4(1, a1)
        DOT4(2, a2)  DOT4(3, a2)
        DOT4(4, a3)
        DOT4(5, a4)  DOT4(6, a4)  DOT4(7, a4)
        DOT4(8, a5)  DOT4(9, a5)  DOT4(10, a5) DOT4(11, a5)
        DOT4(12, a6) DOT4(13, a6)
        DOT4(14, a7) DOT4(15, a7) DOT4(16, a7) DOT4(17, a7)
        DOT4(18, a8) DOT4(19, a8) DOT4(20, a8) DOT4(21, a8)
        DOT4(22, a8) DOT4(23, a8) DOT4(24, a8)
        float* zp = Z + row * 300 + t * 12;
        *(float4*)zp       = make_float4(a0, a1, a2, a3);
        *(float4*)(zp + 4) = make_float4(a4, a5, a6, a7);
        zp[8] = a8;
    }
#undef DOT4
    __syncthreads();

    if (tid < 200) {
        const int t = tid >> 3, dq = tid & 7;
        const int lt = (t >= 16) ? 4 : (t >= 9) ? 3 : (t >= 4) ? 2
                     : (t >= 1) ? 1 : 0;
        const float* vb = Vg + lt * 292 + dq * 4;           // global, L2-warm
        const float4 w0 = *(const float4*)(vb +   0);
        const float4 w1 = *(const float4*)(vb +  32);
        const float4 w2 = *(const float4*)(vb +  64);
        const float4 w3 = *(const float4*)(vb +  96);
        const float4 w4 = *(const float4*)(vb + 128);
        const float4 w5 = *(const float4*)(vb + 160);
        const float4 w6 = *(const float4*)(vb + 192);
        const float4 w7 = *(const float4*)(vb + 224);
        const float4 w8 = *(const float4*)(vb + 256);
#pragma unroll
        for (int row = 0; row < 6; ++row) {
            const float* zp = Z + row * 300 + t * 12;
            const float4 za = *(const float4*)zp;
            const float4 zb = *(const float4*)(zp + 4);
            const float z8 = zp[8];
            float o0 = z8 * w8.x, o1 = z8 * w8.y, o2 = z8 * w8.z, o3 = z8 * w8.w;
            o0 = fmaf(za.x, w0.x, o0); o1 = fmaf(za.x, w0.y, o1);
            o2 = fmaf(za.x, w0.z, o2); o3 = fmaf(za.x, w0.w, o3);
            o0 = fmaf(za.y, w1.x, o0); o1 = fmaf(za.y, w1.y, o1);
            o2 = fmaf(za.y, w1.z, o2); o3 = fmaf(za.y, w1.w, o3);
            o0 = fmaf(za.z, w2.x, o0); o1 = fmaf(za.z, w2.y, o1);
            o2 = fmaf(za.z, w2.z, o2); o3 = fmaf(za.z, w2.w, o3);
            o0 = fmaf(za.w, w3.x, o0); o1 = fmaf(za.w, w3.y, o1);
            o2 = fmaf(za.w, w3.z, o2); o3 = fmaf(za.w, w3.w, o3);
            o0 = fmaf(zb.x, w4.x, o0); o1 = fmaf(zb.x, w4.y, o1);
            o2 = fmaf(zb.x, w4.z, o2); o3 = fmaf(zb.x, w4.w, o3);
            o0 = fmaf(zb.y, w5.x, o0); o1 = fmaf(zb.y, w5.y, o1);
            o2 = fmaf(zb.y, w5.z, o2); o3 = fmaf(zb.y, w5.w, o3);
            o0 = fmaf(zb.z, w6.x, o0); o1 = fmaf(zb.z, w6.y, o1);
            o2 = fmaf(zb.z, w6.z, o2); o3 = fmaf(zb.z, w6.w, o3);
            o0 = fmaf(zb.w, w7.x, o0); o1 = fmaf(zb.w, w7.y, o1);
            o2 = fmaf(zb.w, w7.z, o2); o3 = fmaf(zb.w, w7.w, o3);
            const int zo = (row / 3) * 2400 + (row % 3) * 25 + dq * 300 + t;
            Zout[zo      ] = o0;
            Zout[zo +  75] = o1;
            Zout[zo + 150] = o2;
            Zout[zo + 225] = o3;
        }
    }
    __syncthreads();

    // coalesced copy-out: 4800 floats = 1200 float4, contiguous per block
    float4* og = (float4*)(out + (size_t)n0 * 2400);
    const float4* zo4 = (const float4*)Zout;
    for (int i = tid; i < 1200; i += 256) og[i] = zo4[i];
}

extern "C" void kernel_launch(void* const* d_in, const int* in_sizes, int n_in,
                              void* d_out, int out_size, void* d_ws, size_t ws_size,
                              hipStream_t stream) {
    const float* x    = (const float*)d_in[0];
    const float* y    = (const float*)d_in[1];
    const float* Wx   = (const float*)d_in[2];
    const float* Wy   = (const float*)d_in[3];
    const float* Wz   = (const float*)d_in[4];
    const float* Yin  = (const float*)d_in[5];
    const float* Yout = (const float*)d_in[6];
    const float* wq   = (const float*)d_in[7];
    float* out = (float*)d_out;

    float* Tg = (float*)d_ws;                      // 25*100 = 2500 floats
    float* Vg = Tg + 2500;                         // 5*292 = 1460 floats
    unsigned int* cnt = (unsigned int*)((char*)d_ws + 16384);  // isolated line

    hipMemsetAsync(cnt, 0, sizeof(unsigned int), stream);      // reset counter
    gaunt_fused<<<1024, 256, 0, stream>>>(x, y, Wx, Wy, Wz, Yin, Yout, wq,
                                          Tg, Vg, cnt, out);
}

// Round 19
// 20.348 us; speedup vs baseline: 5.8389x; 5.8389x over previous
//
#include <hip/hip_runtime.h>

// VectorGauntTensorProduct — factored algebraic collapse, 2-launch structure.
// r19 = r16 minus the xs/ys LDS staging: P-phase reads x/y DIRECTLY from
// global (432 B/block, L1-resident, ~11x reuse) — deletes one barrier (4->3)
// and the staging round-trip. Everything else byte-identical to r16.
//
// T[t,pq]  = sum_g wq[g] Yin[g,s] Yin[g,sp] Yout[g,t]       (25x100, block-padded)
// V[lt,b,d]= sum_c Wx[ls,c] Wy[lsp,c] Wz[lt,c,d]            (stride-292 rows)
// P[row,pq]= x[n,a,s] y[n,b,sp] - x[n,b,s] y[n,a,sp]        (row = ni*3+v)
// Z[row,t,b] = sum_{pq in block b} P[row,pq] T[t,pq]
// out[n,d,v,t] = sum_b Z[row,t,b] V[l(t),b,d]
//
// Padded block layout: b = ls*3+lsp, sizes {1,3,5,3,9,15,5,15,25} padded to
// {4,4,8,4,12,16,8,16,28}, starts {0,4,8,16,20,32,48,56,72}, total 100.
// Pads are 0.0 in BOTH T and P.
//
// BUG HISTORY: r4 overlay race; r4-r6 `if(tid<N)` staging bug (STRIDED loops
// only). r9->r10: no direct scatter stores — stage output in LDS, store
// coalesced f4. r15: occupancy beats instruction count. r16: T/V from global
// = neutral. r17: hipLaunchCooperativeKernel never launches here. r18:
// flag-based producer/consumer sync costs ~100us (device-scope release =
// per-XCD L2 writeback; acquire-spin invalidations) — 2-launch is final.

#define GG 380

__device__ __forceinline__ bool decode2(int pq, int& s, int& sp) {
    int b, off;
    if (pq < 16) {
        if (pq < 4)       { b = 0; off = pq; }
        else if (pq < 8)  { b = 1; off = pq - 4; }
        else              { b = 2; off = pq - 8; }
    } else if (pq < 48) {
        if (pq < 20)      { b = 3; off = pq - 16; }
        else if (pq < 32) { b = 4; off = pq - 20; }
        else              { b = 5; off = pq - 32; }
    } else {
        if (pq < 56)      { b = 6; off = pq - 48; }
        else if (pq < 72) { b = 7; off = pq - 56; }
        else              { b = 8; off = pq - 72; }
    }
    int ls = b / 3, lsp = b % 3, w = 2 * lsp + 1;
    if (off >= (2 * ls + 1) * w) return false;
    s  = ls * ls + off / w;
    sp = lsp * lsp + off % w;
    return true;
}

// ---- precomp: T wave-per-entry + V stride-292 (proven, unchanged)
__global__ __launch_bounds__(256) void precomp(const float* __restrict__ Wx,
                                               const float* __restrict__ Wy,
                                               const float* __restrict__ Wz,
                                               const float* __restrict__ Yin,
                                               const float* __restrict__ Yout,
                                               const float* __restrict__ wq,
                                               float* __restrict__ Tg,
                                               float* __restrict__ Vg) {
    int bid = blockIdx.x;
    if (bid < 625) {
        int W = bid * 4 + (threadIdx.x >> 6);     // 0..2499, = t*100 + pq
        int lane = threadIdx.x & 63;
        int t = W / 100, pq = W % 100;
        int s, sp;
        float acc = 0.f;
        if (decode2(pq, s, sp)) {
#pragma unroll
            for (int i = 0; i < 6; ++i) {
                int g = lane + 64 * i;
                if (g < GG)
                    acc = fmaf(wq[g] * Yin[g * 9 + s],
                               Yin[g * 9 + sp] * Yout[g * 25 + t], acc);
            }
        }
#pragma unroll
        for (int m = 32; m; m >>= 1) acc += __shfl_xor(acc, m, 64);
        if (lane == 0) Tg[W] = acc;               // pads write 0
    } else {
        int idx = (bid - 625) * 256 + threadIdx.x;
        if (idx < 1460) {                          // 5 rows * 292 (incl pads)
            int lt = idx / 292, r = idx % 292;
            float acc = 0.f;
            if (r < 288) {
                int b = r / 32, d = r % 32;
                int ls = b / 3, lsp = b % 3;
                for (int c = 0; c < 32; ++c)
                    acc = fmaf(Wx[ls * 32 + c] * Wy[lsp * 32 + c],
                               Wz[lt * 1024 + c * 32 + d], acc);
            }
            Vg[idx] = acc;                         // pad slots -> 0
        }
    }
}

// ---- main: 2 samples/block, 1024 blocks, 256 threads, LDS 28.8 KB.
// LDS floats: Ps[0,600) Z[600,2400) Zout[2400,7200).
// x/y read direct from global (L1); T/V from global (L2).
__global__ __launch_bounds__(256) void gaunt_main(const float* __restrict__ x,
                                                  const float* __restrict__ y,
                                                  const float* __restrict__ Tg,
                                                  const float* __restrict__ Vg,
                                                  float* __restrict__ out) {
    __shared__ __align__(16) float smem[7200];
    float* Ps   = smem;            // 6*100
    float* Z    = smem + 600;      // 6*300
    float* Zout = smem + 2400;     // 4800

    const int tid = threadIdx.x;
    const int n0 = blockIdx.x * 2;
    const float* xb = x + n0 * 27;   // 54 floats, L1-resident
    const float* yb = y + n0 * 27;

    // P[row][100], pads zero — reads x/y direct from global (no staging barrier)
    for (int idx = tid; idx < 600; idx += 256) {
        int row = idx / 100, pq = idx % 100;
        float v = 0.f;
        int s, sp;
        if (decode2(pq, s, sp)) {
            int ni = row / 3, vv = row % 3;
            int a = (vv == 0) ? 1 : ((vv == 1) ? 2 : 0);
            int b = (vv == 0) ? 2 : ((vv == 1) ? 0 : 1);
            v = xb[ni * 27 + a * 9 + s] * yb[ni * 27 + b * 9 + sp]
              - xb[ni * 27 + b * 9 + s] * yb[ni * 27 + a * 9 + sp];
        }
        Ps[idx] = v;
    }
    __syncthreads();

    // Stage A: 150 threads, thread=(t,row); T-f4 from GLOBAL, P-f4 from LDS.
#define DOT4(c, accv) { float4 pv = P4[c], tv = T4[c];                      \
        accv = fmaf(pv.x, tv.x, accv); accv = fmaf(pv.y, tv.y, accv);       \
        accv = fmaf(pv.z, tv.z, accv); accv = fmaf(pv.w, tv.w, accv); }
    if (tid < 150) {
        int t = tid / 6, row = tid % 6;
        const float4* P4 = (const float4*)(Ps + row * 100);
        const float4* T4 = (const float4*)(Tg + t * 100);   // global, L2
        float a0 = 0.f, a1 = 0.f, a2 = 0.f, a3 = 0.f, a4 = 0.f,
              a5 = 0.f, a6 = 0.f, a7 = 0.f, a8 = 0.f;
        DOT4(0, a0)
        DOT4(1, a1)
        DOT4(2, a2)  DOT4(3, a2)
        DOT4(4, a3)
        DOT4(5, a4)  DOT4(6, a4)  DOT4(7, a4)
        DOT4(8, a5)  DOT4(9, a5)  DOT4(10, a5) DOT4(11, a5)
        DOT4(12, a6) DOT4(13, a6)
        DOT4(14, a7) DOT4(15, a7) DOT4(16, a7) DOT4(17, a7)
        DOT4(18, a8) DOT4(19, a8) DOT4(20, a8) DOT4(21, a8)
        DOT4(22, a8) DOT4(23, a8) DOT4(24, a8)
        float* zp = Z + row * 300 + t * 12;
        *(float4*)zp       = make_float4(a0, a1, a2, a3);
        *(float4*)(zp + 4) = make_float4(a4, a5, a6, a7);
        zp[8] = a8;
    }
#undef DOT4
    __syncthreads();

    // Stage B: 200 threads, thread=(t = tid>>3, dq = tid&7); V-f4 from GLOBAL.
    if (tid < 200) {
        const int t = tid >> 3, dq = tid & 7;
        const int lt = (t >= 16) ? 4 : (t >= 9) ? 3 : (t >= 4) ? 2
                     : (t >= 1) ? 1 : 0;
        const float* vb = Vg + lt * 292 + dq * 4;           // global, L2
        const float4 w0 = *(const float4*)(vb +   0);
        const float4 w1 = *(const float4*)(vb +  32);
        const float4 w2 = *(const float4*)(vb +  64);
        const float4 w3 = *(const float4*)(vb +  96);
        const float4 w4 = *(const float4*)(vb + 128);
        const float4 w5 = *(const float4*)(vb + 160);
        const float4 w6 = *(const float4*)(vb + 192);
        const float4 w7 = *(const float4*)(vb + 224);
        const float4 w8 = *(const float4*)(vb + 256);
#pragma unroll
        for (int row = 0; row < 6; ++row) {
            const float* zp = Z + row * 300 + t * 12;
            const float4 za = *(const float4*)zp;
            const float4 zb = *(const float4*)(zp + 4);
            const float z8 = zp[8];
            float o0 = z8 * w8.x, o1 = z8 * w8.y, o2 = z8 * w8.z, o3 = z8 * w8.w;
            o0 = fmaf(za.x, w0.x, o0); o1 = fmaf(za.x, w0.y, o1);
            o2 = fmaf(za.x, w0.z, o2); o3 = fmaf(za.x, w0.w, o3);
            o0 = fmaf(za.y, w1.x, o0); o1 = fmaf(za.y, w1.y, o1);
            o2 = fmaf(za.y, w1.z, o2); o3 = fmaf(za.y, w1.w, o3);
            o0 = fmaf(za.z, w2.x, o0); o1 = fmaf(za.z, w2.y, o1);
            o2 = fmaf(za.z, w2.z, o2); o3 = fmaf(za.z, w2.w, o3);
            o0 = fmaf(za.w, w3.x, o0); o1 = fmaf(za.w, w3.y, o1);
            o2 = fmaf(za.w, w3.z, o2); o3 = fmaf(za.w, w3.w, o3);
            o0 = fmaf(zb.x, w4.x, o0); o1 = fmaf(zb.x, w4.y, o1);
            o2 = fmaf(zb.x, w4.z, o2); o3 = fmaf(zb.x, w4.w, o3);
            o0 = fmaf(zb.y, w5.x, o0); o1 = fmaf(zb.y, w5.y, o1);
            o2 = fmaf(zb.y, w5.z, o2); o3 = fmaf(zb.y, w5.w, o3);
            o0 = fmaf(zb.z, w6.x, o0); o1 = fmaf(zb.z, w6.y, o1);
            o2 = fmaf(zb.z, w6.z, o2); o3 = fmaf(zb.z, w6.w, o3);
            o0 = fmaf(zb.w, w7.x, o0); o1 = fmaf(zb.w, w7.y, o1);
            o2 = fmaf(zb.w, w7.z, o2); o3 = fmaf(zb.w, w7.w, o3);
            const int zo = (row / 3) * 2400 + (row % 3) * 25 + dq * 300 + t;
            Zout[zo      ] = o0;
            Zout[zo +  75] = o1;
            Zout[zo + 150] = o2;
            Zout[zo + 225] = o3;
        }
    }
    __syncthreads();

    // coalesced copy-out: 4800 floats = 1200 float4, contiguous per block
    float4* og = (float4*)(out + (size_t)n0 * 2400);
    const float4* zo4 = (const float4*)Zout;
    for (int i = tid; i < 1200; i += 256) og[i] = zo4[i];
}

extern "C" void kernel_launch(void* const* d_in, const int* in_sizes, int n_in,
                              void* d_out, int out_size, void* d_ws, size_t ws_size,
                              hipStream_t stream) {
    const float* x    = (const float*)d_in[0];
    const float* y    = (const float*)d_in[1];
    const float* Wx   = (const float*)d_in[2];
    const float* Wy   = (const float*)d_in[3];
    const float* Wz   = (const float*)d_in[4];
    const float* Yin  = (const float*)d_in[5];
    const float* Yout = (const float*)d_in[6];
    const float* wq   = (const float*)d_in[7];
    float* out = (float*)d_out;

    float* Tg = (float*)d_ws;        // 25*100 = 2500 floats
    float* Vg = Tg + 2500;           // 5*292 = 1460 floats (16B-aligned)

    precomp<<<631, 256, 0, stream>>>(Wx, Wy, Wz, Yin, Yout, wq, Tg, Vg);
    gaunt_main<<<1024, 256, 0, stream>>>(x, y, Tg, Vg, out);
}

// Round 20
// 19.960 us; speedup vs baseline: 5.9524x; 1.0194x over previous
//
#include <hip/hip_runtime.h>

// VectorGauntTensorProduct — factored algebraic collapse, 2-launch structure.
// FINAL (champion r14, 19.96 us): stage A thread=(t,row) f4-chunk dots with
// LDS T; stage B thread=(t,dq) with 9 V-f4 hoisted; Zout LDS transpose +
// coalesced f4 copy-out; 2 samples/block, 1024 blocks, 35.5 KB LDS
// (4 blocks/CU, one latency round).
//
// T[t,pq]  = sum_g wq[g] Yin[g,s] Yin[g,sp] Yout[g,t]       (25x100, block-padded)
// V[lt,b,d]= sum_c Wx[ls,c] Wy[lsp,c] Wz[lt,c,d]            (stride-292 rows)
// P[row,pq]= x[n,a,s] y[n,b,sp] - x[n,b,s] y[n,a,sp]        (row = ni*3+v)
// Z[row,t,b] = sum_{pq in block b} P[row,pq] T[t,pq]
// out[n,d,v,t] = sum_b Z[row,t,b] V[l(t),b,d]
//
// Padded block layout: b = ls*3+lsp, sizes {1,3,5,3,9,15,5,15,25} padded to
// {4,4,8,4,12,16,8,16,28}, starts {0,4,8,16,20,32,48,56,72}, total 100.
// Pads are 0.0 in BOTH T and P. V stride 292 de-aliases lt bank groups.
//
// SESSION LESSONS (r0-r19):
//  - algebraic collapse: 25M-point grid -> 57M FMA factored bilinear form.
//  - r4 overlay race; r4-r6 `if(tid<N)` staging bug -> STRIDED loops only.
//  - r9->r10: direct scatter stores amplify L2 write sectors ~16x -> stage
//    output in LDS, store coalesced f4 (+4.5us).
//  - r10->r11: co-residency (one latency round) +3.6us; r15: halving
//    blocks/CU regresses even when per-instr work drops.
//  - r12/r13: LDS-instruction count matters, but never concentrate a phase
//    into <1 wave/block; no runtime-indexed register arrays.
//  - r16/r19: T/V from global (L2) and staging/barrier removal = neutral ->
//    main is latency-bound on its phase chain, not issue-bound.
//  - r17: hipLaunchCooperativeKernel never launches in this harness.
//  - r18: flag-based cross-block sync costs ~100us on non-coherent XCD L2s.
//  => ~20us is this decomposition's practical floor here.

#define GG 380

__device__ __forceinline__ bool decode2(int pq, int& s, int& sp) {
    int b, off;
    if (pq < 16) {
        if (pq < 4)       { b = 0; off = pq; }
        else if (pq < 8)  { b = 1; off = pq - 4; }
        else              { b = 2; off = pq - 8; }
    } else if (pq < 48) {
        if (pq < 20)      { b = 3; off = pq - 16; }
        else if (pq < 32) { b = 4; off = pq - 20; }
        else              { b = 5; off = pq - 32; }
    } else {
        if (pq < 56)      { b = 6; off = pq - 48; }
        else if (pq < 72) { b = 7; off = pq - 56; }
        else              { b = 8; off = pq - 72; }
    }
    int ls = b / 3, lsp = b % 3, w = 2 * lsp + 1;
    if (off >= (2 * ls + 1) * w) return false;
    s  = ls * ls + off / w;
    sp = lsp * lsp + off % w;
    return true;
}

// ---- precomp: T wave-per-entry + V stride-292
__global__ __launch_bounds__(256) void precomp(const float* __restrict__ Wx,
                                               const float* __restrict__ Wy,
                                               const float* __restrict__ Wz,
                                               const float* __restrict__ Yin,
                                               const float* __restrict__ Yout,
                                               const float* __restrict__ wq,
                                               float* __restrict__ Tg,
                                               float* __restrict__ Vg) {
    int bid = blockIdx.x;
    if (bid < 625) {
        int W = bid * 4 + (threadIdx.x >> 6);     // 0..2499, = t*100 + pq
        int lane = threadIdx.x & 63;
        int t = W / 100, pq = W % 100;
        int s, sp;
        float acc = 0.f;
        if (decode2(pq, s, sp)) {
#pragma unroll
            for (int i = 0; i < 6; ++i) {
                int g = lane + 64 * i;
                if (g < GG)
                    acc = fmaf(wq[g] * Yin[g * 9 + s],
                               Yin[g * 9 + sp] * Yout[g * 25 + t], acc);
            }
        }
#pragma unroll
        for (int m = 32; m; m >>= 1) acc += __shfl_xor(acc, m, 64);
        if (lane == 0) Tg[W] = acc;               // pads write 0
    } else {
        int idx = (bid - 625) * 256 + threadIdx.x;
        if (idx < 1460) {                          // 5 rows * 292 (incl pads)
            int lt = idx / 292, r = idx % 292;
            float acc = 0.f;
            if (r < 288) {
                int b = r / 32, d = r % 32;
                int ls = b / 3, lsp = b % 3;
                for (int c = 0; c < 32; ++c)
                    acc = fmaf(Wx[ls * 32 + c] * Wy[lsp * 32 + c],
                               Wz[lt * 1024 + c * 32 + d], acc);
            }
            Vg[idx] = acc;                         // pad slots -> 0
        }
    }
}

// ---- main: 2 samples/block, 1024 blocks, 256 threads, LDS 35.5 KB.
// LDS floats: xs[0,108)* ys[108,216)* Ps[216,816) Vs[816,2276) Z[2276,4076)
//             Ts[4076,6576) | Zout[4076,8876) overlays Ts (dead after A).
__global__ __launch_bounds__(256) void gaunt_main(const float* __restrict__ x,
                                                  const float* __restrict__ y,
                                                  const float* __restrict__ Tg,
                                                  const float* __restrict__ Vg,
                                                  float* __restrict__ out) {
    __shared__ __align__(16) float smem[8876];
    float* xs   = smem;            // 54 used
    float* ys   = smem + 108;      // 54 used
    float* Ps   = smem + 216;      // 6*100
    float* Vs   = smem + 816;      // 5*292
    float* Z    = smem + 2276;     // 6*300
    float* Ts   = smem + 4076;     // 25*100 (dead after stage A)
    float* Zout = smem + 4076;     // 4800 (stage B + copy-out only)

    const int tid = threadIdx.x;
    const int n0 = blockIdx.x * 2;

    if (tid < 54)       xs[tid]      = x[n0 * 27 + tid];
    else if (tid < 108) ys[tid - 54] = y[n0 * 27 + tid - 54];
    for (int i = tid; i < 625; i += 256)            // Ts: 2500 floats
        ((float4*)Ts)[i] = ((const float4*)Tg)[i];
    for (int i = tid; i < 365; i += 256)            // Vs: 1460 floats (strided)
        ((float4*)Vs)[i] = ((const float4*)Vg)[i];
    __syncthreads();

    // P[row][100], pads zero
    for (int idx = tid; idx < 600; idx += 256) {
        int row = idx / 100, pq = idx % 100;
        float v = 0.f;
        int s, sp;
        if (decode2(pq, s, sp)) {
            int ni = row / 3, vv = row % 3;
            int a = (vv == 0) ? 1 : ((vv == 1) ? 2 : 0);
            int b = (vv == 0) ? 2 : ((vv == 1) ? 0 : 1);
            v = xs[ni * 27 + a * 9 + s] * ys[ni * 27 + b * 9 + sp]
              - xs[ni * 27 + b * 9 + s] * ys[ni * 27 + a * 9 + sp];
        }
        Ps[idx] = v;
    }
    __syncthreads();

    // Stage A: 150 threads, thread=(t,row); 25 f4-chunk dots -> 9 block sums
#define DOT4(c, accv) { float4 pv = P4[c], tv = T4[c];                      \
        accv = fmaf(pv.x, tv.x, accv); accv = fmaf(pv.y, tv.y, accv);       \
        accv = fmaf(pv.z, tv.z, accv); accv = fmaf(pv.w, tv.w, accv); }
    if (tid < 150) {
        int t = tid / 6, row = tid % 6;
        const float4* P4 = (const float4*)(Ps + row * 100);
        const float4* T4 = (const float4*)(Ts + t * 100);
        float a0 = 0.f, a1 = 0.f, a2 = 0.f, a3 = 0.f, a4 = 0.f,
              a5 = 0.f, a6 = 0.f, a7 = 0.f, a8 = 0.f;
        DOT4(0, a0)
        DOT4(1, a1)
        DOT4(2, a2)  DOT4(3, a2)
        DOT4(4, a3)
        DOT4(5, a4)  DOT4(6, a4)  DOT4(7, a4)
        DOT4(8, a5)  DOT4(9, a5)  DOT4(10, a5) DOT4(11, a5)
        DOT4(12, a6) DOT4(13, a6)
        DOT4(14, a7) DOT4(15, a7) DOT4(16, a7) DOT4(17, a7)
        DOT4(18, a8) DOT4(19, a8) DOT4(20, a8) DOT4(21, a8)
        DOT4(22, a8) DOT4(23, a8) DOT4(24, a8)
        float* zp = Z + row * 300 + t * 12;
        *(float4*)zp       = make_float4(a0, a1, a2, a3);
        *(float4*)(zp + 4) = make_float4(a4, a5, a6, a7);
        zp[8] = a8;
    }
#undef DOT4
    __syncthreads();
    // ---- Ts DEAD from here; Zout (overlaying it) becomes live ----

    // Stage B: 200 threads, thread = (t = tid>>3, dq = tid&7).
    // Hoist 9 V-f4 once; uniform 6-row loop: Z broadcast reads, 36 FMA,
    // 4 Zout writes per row.
    if (tid < 200) {
        const int t = tid >> 3, dq = tid & 7;
        const int lt = (t >= 16) ? 4 : (t >= 9) ? 3 : (t >= 4) ? 2
                     : (t >= 1) ? 1 : 0;
        const float* vb = Vs + lt * 292 + dq * 4;
        const float4 w0 = *(const float4*)(vb +   0);
        const float4 w1 = *(const float4*)(vb +  32);
        const float4 w2 = *(const float4*)(vb +  64);
        const float4 w3 = *(const float4*)(vb +  96);
        const float4 w4 = *(const float4*)(vb + 128);
        const float4 w5 = *(const float4*)(vb + 160);
        const float4 w6 = *(const float4*)(vb + 192);
        const float4 w7 = *(const float4*)(vb + 224);
        const float4 w8 = *(const float4*)(vb + 256);
#pragma unroll
        for (int row = 0; row < 6; ++row) {
            const float* zp = Z + row * 300 + t * 12;
            const float4 za = *(const float4*)zp;
            const float4 zb = *(const float4*)(zp + 4);
            const float z8 = zp[8];
            float o0 = z8 * w8.x, o1 = z8 * w8.y, o2 = z8 * w8.z, o3 = z8 * w8.w;
            o0 = fmaf(za.x, w0.x, o0); o1 = fmaf(za.x, w0.y, o1);
            o2 = fmaf(za.x, w0.z, o2); o3 = fmaf(za.x, w0.w, o3);
            o0 = fmaf(za.y, w1.x, o0); o1 = fmaf(za.y, w1.y, o1);
            o2 = fmaf(za.y, w1.z, o2); o3 = fmaf(za.y, w1.w, o3);
            o0 = fmaf(za.z, w2.x, o0); o1 = fmaf(za.z, w2.y, o1);
            o2 = fmaf(za.z, w2.z, o2); o3 = fmaf(za.z, w2.w, o3);
            o0 = fmaf(za.w, w3.x, o0); o1 = fmaf(za.w, w3.y, o1);
            o2 = fmaf(za.w, w3.z, o2); o3 = fmaf(za.w, w3.w, o3);
            o0 = fmaf(zb.x, w4.x, o0); o1 = fmaf(zb.x, w4.y, o1);
            o2 = fmaf(zb.x, w4.z, o2); o3 = fmaf(zb.x, w4.w, o3);
            o0 = fmaf(zb.y, w5.x, o0); o1 = fmaf(zb.y, w5.y, o1);
            o2 = fmaf(zb.y, w5.z, o2); o3 = fmaf(zb.y, w5.w, o3);
            o0 = fmaf(zb.z, w6.x, o0); o1 = fmaf(zb.z, w6.y, o1);
            o2 = fmaf(zb.z, w6.z, o2); o3 = fmaf(zb.z, w6.w, o3);
            o0 = fmaf(zb.w, w7.x, o0); o1 = fmaf(zb.w, w7.y, o1);
            o2 = fmaf(zb.w, w7.z, o2); o3 = fmaf(zb.w, w7.w, o3);
            const int zo = (row / 3) * 2400 + (row % 3) * 25 + dq * 300 + t;
            Zout[zo      ] = o0;
            Zout[zo +  75] = o1;
            Zout[zo + 150] = o2;
            Zout[zo + 225] = o3;
        }
    }
    __syncthreads();

    // coalesced copy-out: 4800 floats = 1200 float4, contiguous per block
    float4* og = (float4*)(out + (size_t)n0 * 2400);
    const float4* zo4 = (const float4*)Zout;
    for (int i = tid; i < 1200; i += 256) og[i] = zo4[i];
}

extern "C" void kernel_launch(void* const* d_in, const int* in_sizes, int n_in,
                              void* d_out, int out_size, void* d_ws, size_t ws_size,
                              hipStream_t stream) {
    const float* x    = (const float*)d_in[0];
    const float* y    = (const float*)d_in[1];
    const float* Wx   = (const float*)d_in[2];
    const float* Wy   = (const float*)d_in[3];
    const float* Wz   = (const float*)d_in[4];
    const float* Yin  = (const float*)d_in[5];
    const float* Yout = (const float*)d_in[6];
    const float* wq   = (const float*)d_in[7];
    float* out = (float*)d_out;

    float* Tg = (float*)d_ws;        // 25*100 = 2500 floats
    float* Vg = Tg + 2500;           // 5*292 = 1460 floats (16B-aligned)

    precomp<<<631, 256, 0, stream>>>(Wx, Wy, Wz, Yin, Yout, wq, Tg, Vg);
    gaunt_main<<<1024, 256, 0, stream>>>(x, y, Tg, Vg, out);
}